// Round 1
// 1031.048 us; speedup vs baseline: 2.8582x; 2.8582x over previous
//
#include <hip/hip_runtime.h>

// FNO spectral conv: B=32, L=4096, D=E=512, MODES=64.
// out = irfft( einsum("bmd,dem->bme", rfft(q)[:, :64, :], Wr + i*Wi), n=L )
//
// Decomposed into truncated-DFT GEMMs (only 64 of 2049 modes survive):
//   S1: F[b,d,m] (cplx) = sum_l q[b,l,d] * exp(-2pi i m l / L)
//   S2: G[b,m,e] (cplx) = sum_d F * (Wr + i Wi)[d,e,m]
//   S3: out[b,l,e] = (1/L)*Gr[b,0,e] + sum_{m>=1} (2/L)(Gr*cos - Gi*sin)(2pi m l/L)
//
// This revision: stages 1 and 3 are LDS-tiled fp32 GEMMs (the previous
// wave-uniform-table version was latency-bound at 17% VALUBusy).

#define NB 32
#define NL 4096
#define ND 512
#define NE 512
#define NM 64

#define FELEMS (NB * ND * NM)   // float2 elements in Ft            (1,048,576)
#define FPCH   (NB * ND * 128)  // floats per stage-1 partial chunk (2,097,152)
#define HELEMS (NB * 128 * NE)  // floats in one H buffer           (2,097,152)

// ---------------------------------------------------------------- basis tables
// fwdT[l][k]  (l-major, for stage1 B-operand): k<64: cos(2pi k l/L); k>=64: -sin
// invTT[k][l] (k-major, for stage3 A-operand): k<64: cos(2pi k l/L); k>=64: +sin
__global__ __launch_bounds__(256) void build_tables_k(float* __restrict__ fwdT,
                                                      float* __restrict__ invTT) {
  int idx = blockIdx.x * 256 + threadIdx.x;
  if (idx >= NL * NM) return;
  {
    int l = idx >> 6, m = idx & (NM - 1);
    int p = (m * l) & (NL - 1);           // exact phase reduction mod L
    double s, c;
    sincospi((double)p / (double)(NL / 2), &s, &c);
    fwdT[l * 128 + m]      = (float)c;
    fwdT[l * 128 + 64 + m] = (float)(-s);
  }
  {
    int l = idx & (NL - 1), m = idx >> 12;  // coalesced along l
    int p = (m * l) & (NL - 1);
    double s, c;
    sincospi((double)p / (double)(NL / 2), &s, &c);
    invTT[m * NL + l]        = (float)c;
    invTT[(64 + m) * NL + l] = (float)s;
  }
}

// ---------------------------------------------------------------- stage 1
// Per (b, l-chunk): C[d, m] = sum_l q[b,l,d] * fwdT[l,m].  Both operands are
// l-major -> LDS staging is a straight coalesced copy.  Tile 64d x 128m,
// 256 threads, 4x8 acc/thread, K staged 64 l at a time. 48 KB LDS -> 3 blk/CU.
__global__ __launch_bounds__(256) void stage1_k(const float* __restrict__ q,
                                                const float* __restrict__ fwdT,
                                                float* __restrict__ Fp,
                                                int lchunk) {
  __shared__ __align__(16) float qs[64][64];    // [l][d]
  __shared__ __align__(16) float bs[64][128];   // [l][m]
  const int t  = threadIdx.x;
  const int d0 = blockIdx.x * 64;
  const int b  = blockIdx.y;
  const int l0 = blockIdx.z * lchunk;
  const int td = (t & 15) * 4;   // 16 distinct -> 2-way bank alias (free)
  const int tm = (t >> 4) * 8;   // 4 distinct per wave -> broadcast
  float acc[4][8];
#pragma unroll
  for (int i = 0; i < 4; ++i)
#pragma unroll
    for (int j = 0; j < 8; ++j) acc[i][j] = 0.f;

  for (int ls = l0; ls < l0 + lchunk; ls += 64) {
    __syncthreads();
    // qs: 64x64 floats = 1024 float4, 4 per thread, fully coalesced
#pragma unroll
    for (int i = 0; i < 4; ++i) {
      int f = t + 256 * i;
      int r = f >> 4, c4 = (f & 15) * 4;
      *(float4*)&qs[r][c4] =
          *(const float4*)&q[((size_t)b * NL + ls + r) * ND + d0 + c4];
    }
    // bs: 64x128 floats = 2048 float4, 8 per thread, fully coalesced
#pragma unroll
    for (int i = 0; i < 8; ++i) {
      int f = t + 256 * i;
      int r = f >> 5, c4 = (f & 31) * 4;
      *(float4*)&bs[r][c4] =
          *(const float4*)&fwdT[(size_t)(ls + r) * 128 + c4];
    }
    __syncthreads();
#pragma unroll 4
    for (int l = 0; l < 64; ++l) {
      float4 a  = *(const float4*)&qs[l][td];
      float4 b0 = *(const float4*)&bs[l][tm];
      float4 b1 = *(const float4*)&bs[l][tm + 4];
      float av[4] = {a.x, a.y, a.z, a.w};
      float bv[8] = {b0.x, b0.y, b0.z, b0.w, b1.x, b1.y, b1.z, b1.w};
#pragma unroll
      for (int i = 0; i < 4; ++i)
#pragma unroll
        for (int j = 0; j < 8; ++j) acc[i][j] = fmaf(av[i], bv[j], acc[i][j]);
    }
  }
  // Fp[c][b][d][mcol]: mcol<64 = Re, mcol>=64 = Im (unscaled partials)
  float* o = Fp + (size_t)blockIdx.z * FPCH;
#pragma unroll
  for (int i = 0; i < 4; ++i) {
    size_t row = ((size_t)b * ND + d0 + td + i) * 128 + tm;
    *(float4*)&o[row]     = make_float4(acc[i][0], acc[i][1], acc[i][2], acc[i][3]);
    *(float4*)&o[row + 4] = make_float4(acc[i][4], acc[i][5], acc[i][6], acc[i][7]);
  }
}

__global__ __launch_bounds__(256) void reduceF_k(const float* __restrict__ Fp,
                                                 float2* __restrict__ Ft, int FS) {
  int idx = blockIdx.x * 256 + threadIdx.x;
  if (idx >= FELEMS) return;
  int m = idx & 63;
  size_t base = (size_t)(idx >> 6) * 128 + m;
  float xr = 0.f, xi = 0.f;
  for (int c = 0; c < FS; ++c) {
    xr += Fp[(size_t)c * FPCH + base];
    xi += Fp[(size_t)c * FPCH + base + 64];
  }
  Ft[idx] = make_float2(xr, xi);
}

// ---------------------------------------------------------------- stage 2
// lane = mode (the coalesced direction of W[D][E][64]). Each wave: 8 batches x
// 8 e-columns in registers; block = 4 waves covering all 32 batches of one
// 8-e tile, sharing W through L1. d-split over blockIdx.y into partials.
__global__ __launch_bounds__(256) void stage2_k(const float2* __restrict__ Ft,
                                                const float* __restrict__ Wr,
                                                const float* __restrict__ Wi,
                                                float* __restrict__ Hp,
                                                int dlen) {
  const int lane = threadIdx.x & 63;  // mode
  const int bg   = threadIdx.x >> 6;  // batch group (8 batches)
  const int e0 = blockIdx.x * 8;
  const int c  = blockIdx.y;
  const int d0 = c * dlen;
  float accr[8][8], acci[8][8];
#pragma unroll
  for (int jb = 0; jb < 8; ++jb)
#pragma unroll
    for (int je = 0; je < 8; ++je) { accr[jb][je] = 0.f; acci[jb][je] = 0.f; }

  for (int d = d0; d < d0 + dlen; ++d) {
    float wr[8], wi[8];
#pragma unroll
    for (int je = 0; je < 8; ++je) {
      size_t widx = ((size_t)d * NE + (e0 + je)) * NM + lane;
      wr[je] = Wr[widx];
      wi[je] = Wi[widx];
    }
#pragma unroll
    for (int jb = 0; jb < 8; ++jb) {
      float2 f = Ft[((size_t)(bg * 8 + jb) * ND + d) * NM + lane];
#pragma unroll
      for (int je = 0; je < 8; ++je) {
        accr[jb][je] = fmaf(f.x,  wr[je], accr[jb][je]);
        accr[jb][je] = fmaf(-f.y, wi[je], accr[jb][je]);
        acci[jb][je] = fmaf(f.x,  wi[je], acci[jb][je]);
        acci[jb][je] = fmaf(f.y,  wr[je], acci[jb][je]);
      }
    }
  }
  // Hp[c][b][k][e]: k<64 holds Gr (real), k>=64 holds Gi (imag), unscaled.
#pragma unroll
  for (int jb = 0; jb < 8; ++jb) {
    int b = bg * 8 + jb;
    size_t base = (size_t)c * HELEMS + ((size_t)b * 128) * NE;
#pragma unroll
    for (int je = 0; je < 8; ++je) {
      Hp[base + (size_t)lane * NE + (e0 + je)]        = accr[jb][je];
      Hp[base + (size_t)(64 + lane) * NE + (e0 + je)] = acci[jb][je];
    }
  }
}

// Reduce d-split partials and fold in the irfft scaling:
//   k<64  (cos coeff):  (k==0 ? 1 : 2)/L * Gr
//   k>=64 (sin coeff):  (m==0 ? 0 : -2/L) * Gi      (DC imag dropped by irfft)
__global__ __launch_bounds__(256) void reduceH_k(const float* __restrict__ Hp,
                                                 float* __restrict__ H, int DS) {
  int idx = blockIdx.x * 256 + threadIdx.x;
  if (idx >= HELEMS) return;
  float s = 0.f;
  for (int c = 0; c < DS; ++c) s += Hp[(size_t)c * HELEMS + idx];
  int k = (idx >> 9) & 127;
  float scale;
  if (k < 64) scale = (k == 0 ? 1.0f : 2.0f) / (float)NL;
  else        scale = (k == 64 ? 0.0f : -2.0f / (float)NL);
  H[idx] = s * scale;
}

// ---------------------------------------------------------------- stage 3
// Per b: out[4096 x 512] = invT[4096 x 128] * H[128 x 512].  K=128 fits in
// LDS entirely: At[k][l] 32 KB + Bt[k][e] 32 KB, staged once per block.
// Tile 64l x 64e, 256 threads, 4x4 acc/thread. 64 KB LDS -> 2 blk/CU.
__global__ __launch_bounds__(256) void stage3_k(const float* __restrict__ H,
                                                const float* __restrict__ invTT,
                                                float* __restrict__ out) {
  __shared__ __align__(16) float At[128][64];  // [k][l]
  __shared__ __align__(16) float Bt[128][64];  // [k][e]
  const int t  = threadIdx.x;
  const int e0 = blockIdx.x * 64;
  const int b  = blockIdx.y;
  const int l0 = blockIdx.z * 64;
  // stage both tiles: 2 x 2048 float4, 8 float4 per thread each, coalesced
#pragma unroll
  for (int i = 0; i < 8; ++i) {
    int f = t + 256 * i;
    int k = f >> 4, c4 = (f & 15) * 4;
    *(float4*)&At[k][c4] = *(const float4*)&invTT[(size_t)k * NL + l0 + c4];
    *(float4*)&Bt[k][c4] =
        *(const float4*)&H[((size_t)b * 128 + k) * NE + e0 + c4];
  }
  __syncthreads();
  const int te = (t & 15) * 4;   // 16 distinct -> 2-way bank alias (free)
  const int tl = (t >> 4) * 4;   // 4 distinct per wave -> broadcast
  float acc[4][4];
#pragma unroll
  for (int i = 0; i < 4; ++i)
#pragma unroll
    for (int j = 0; j < 4; ++j) acc[i][j] = 0.f;
#pragma unroll 8
  for (int k = 0; k < 128; ++k) {
    float4 a  = *(const float4*)&At[k][tl];
    float4 bv = *(const float4*)&Bt[k][te];
    float av[4] = {a.x, a.y, a.z, a.w};
    float bb[4] = {bv.x, bv.y, bv.z, bv.w};
#pragma unroll
    for (int i = 0; i < 4; ++i)
#pragma unroll
      for (int j = 0; j < 4; ++j) acc[i][j] = fmaf(av[i], bb[j], acc[i][j]);
  }
#pragma unroll
  for (int i = 0; i < 4; ++i) {
    *(float4*)&out[((size_t)b * NL + l0 + tl + i) * NE + e0 + te] =
        make_float4(acc[i][0], acc[i][1], acc[i][2], acc[i][3]);
  }
}

// ---------------------------------------------------------------- launch
extern "C" void kernel_launch(void* const* d_in, const int* in_sizes, int n_in,
                              void* d_out, int out_size, void* d_ws, size_t ws_size,
                              hipStream_t stream) {
  const float* q  = (const float*)d_in[0];
  const float* Wr = (const float*)d_in[1];
  const float* Wi = (const float*)d_in[2];
  float* out = (float*)d_out;
  float* ws  = (float*)d_ws;

  // ws layout (floats): fwdT | invTT | Ft | H | scratch(Fp or Hp)
  float*  fwdT  = ws;                           // 524,288
  float*  invTT = ws + 524288;                  // 524,288
  float2* Ft    = (float2*)(ws + 1048576);      // 1,048,576 float2
  float*  H     = ws + 1048576 + 2097152;       // 2,097,152
  float*  scratch = ws + 1048576 + 2097152 + 2097152;

  const size_t base_bytes = (size_t)5242880 * 4u;   // 20 MiB
  const size_t CH = (size_t)FPCH * 4u;              // 8 MiB per scratch chunk
  int FS = 1, DS = 1;                               // l-split / d-split factors
  if      (ws_size >= base_bytes + 16 * CH) { FS = 16; DS = 8; }
  else if (ws_size >= base_bytes + 8 * CH)  { FS = 8;  DS = 8; }
  else if (ws_size >= base_bytes + 4 * CH)  { FS = 4;  DS = 4; }
  else if (ws_size >= base_bytes + 2 * CH)  { FS = 2;  DS = 2; }

  build_tables_k<<<(NL * NM + 255) / 256, 256, 0, stream>>>(fwdT, invTT);
  stage1_k<<<dim3(ND / 64, NB, FS), 256, 0, stream>>>(q, fwdT, scratch, NL / FS);
  reduceF_k<<<(FELEMS + 255) / 256, 256, 0, stream>>>(scratch, Ft, FS);
  stage2_k<<<dim3(NE / 8, DS), 256, 0, stream>>>(Ft, Wr, Wi, scratch, ND / DS);
  reduceH_k<<<(HELEMS + 255) / 256, 256, 0, stream>>>(scratch, H, DS);
  stage3_k<<<dim3(NE / 64, NB, NL / 64), 256, 0, stream>>>(H, invTT, out);
}